// Round 9
// baseline (245.398 us; speedup 1.0000x reference)
//
#include <hip/hip_runtime.h>
#include <hip/hip_fp16.h>

typedef _Float16 half8  __attribute__((ext_vector_type(8)));
typedef _Float16 half4_t __attribute__((ext_vector_type(4)));
typedef _Float16 half2_t __attribute__((ext_vector_type(2)));
typedef float f32x4 __attribute__((ext_vector_type(4)));

namespace {
constexpr int NT = 256;
constexpr int NPIX = 225;
constexpr int PCODE_C = 2380;

// A_pad[6][17][17] half8 slots: row pitch 272 B, cg pitch 4624 B
constexpr int APITCH_Y  = 272;
constexpr int APITCH_CG = 4624;
constexpr int XPITCH = 112;   // X row pitch (48 f16 data + pad)

// ---- LDS layout (byte offsets) ----
constexpr int OFF_A     = 0;       // A_pad 27744; ALIASED by X (240*112=26880) after barrier 2
constexpr int OFF_X     = 0;
constexpr int OFF_POLA  = 26880;   // PolA_pad[2][17][17] slots = 9248 -> ends 36128
constexpr int OFF_WC    = 36128;   // dw conv w  f16 [6][9][8]  = 864
constexpr int OFF_WCB   = 36992;   // dw conv b  f16 [6][8]     = 96
constexpr int OFF_WPD   = 37088;   // pol dw w   f16 [2][9][8]  = 288
constexpr int OFF_WPDB  = 37376;   // pol dw b   f16 [2][8]     = 32
constexpr int OFF_SV    = 37408;   // f32[32] = 128
constexpr int OFF_H1    = 37536;   // f32[32] = 128
constexpr int OFF_H2    = 37664;   // f32[32] = 128
constexpr int SMEM_BYTES = 37792;  // 4 blocks/CU (4*37792 = 151168 < 163840)
}

__device__ __forceinline__ half2_t pkrtz(float a, float b) {
    return __builtin_bit_cast(half2_t, __builtin_amdgcn_cvt_pkrtz(a, b));
}
__device__ __forceinline__ void wave_fence() {
    asm volatile("s_waitcnt lgkmcnt(0)" ::: "memory");
}

__global__ __launch_bounds__(NT, 4) void patnet_kernel(
    const float* __restrict__ emb,
    const float* __restrict__ conv_w, const float* __restrict__ conv_b,
    const float* __restrict__ ppw_w,  const float* __restrict__ ppw_b,
    const float* __restrict__ pdw_w,  const float* __restrict__ pdw_b,
    const float* __restrict__ pf_w,
    const float* __restrict__ vpw_w,  const float* __restrict__ vpw_b,
    const float* __restrict__ vl1_w,  const float* __restrict__ vl1_b,
    const float* __restrict__ vl2_w,  const float* __restrict__ vl2_b,
    const float* __restrict__ vf_w,   const float* __restrict__ vf_b,
    const int* __restrict__ sparse,   const int* __restrict__ board,
    float* __restrict__ out, int batch)
{
    __shared__ __align__(16) unsigned char smem[SMEM_BYTES];
    const int tid  = threadIdx.x;
    const int b    = blockIdx.x;
    const int lane = tid & 63;
    const int wave = tid >> 6;

    // ---- issue code loads first (deep prefetch) ----
    int c0 = 0, c1 = 0;
    if (tid < NPIX) {
        int s10 = sparse[b * 2700 + 10 * NPIX + tid];
        int s11 = sparse[b * 2700 + 11 * NPIX + tid];
        int b0  = board[b * 450 + tid];
        int b1  = board[b * 450 + NPIX + tid];
        c0 = (b0 > 0) ? PCODE_C : s10;
        c1 = ((b1 > 0) ? PCODE_C : s11) + (PCODE_C + 1);
    }

    // ---- P0: stage depthwise weight tables (transposed) + zero A pads ----
    {
        _Float16* Wc   = (_Float16*)(smem + OFF_WC);
        _Float16* Wcb  = (_Float16*)(smem + OFF_WCB);
        _Float16* Wpd  = (_Float16*)(smem + OFF_WPD);
        _Float16* Wpdb = (_Float16*)(smem + OFF_WPDB);
        for (int i = tid; i < 432; i += NT) {     // Wc[cg][tap][j] = conv_w[(cg*8+j)*9+tap]
            int cg = i / 72, rem = i - cg * 72;
            int t = rem >> 3, j = rem & 7;
            Wc[i] = (_Float16)conv_w[(cg * 8 + j) * 9 + t];
        }
        for (int i = tid; i < 48; i += NT) Wcb[i] = (_Float16)conv_b[i];
        for (int i = tid; i < 144; i += NT) {
            int cg = i / 72, rem = i - cg * 72;
            int t = rem >> 3, j = rem & 7;
            Wpd[i] = (_Float16)pdw_w[(cg * 8 + j) * 9 + t];
        }
        for (int i = tid; i < 16; i += NT) Wpdb[i] = (_Float16)pdw_b[i];
        // zero A_pad borders: 64 slots per cg
        for (int i = tid; i < 384; i += NT) {
            int cg = i >> 6, j = i & 63;
            int row, col;
            if (j < 17)      { row = 0;  col = j; }
            else if (j < 34) { row = 16; col = j - 17; }
            else { int k = j - 34; row = 1 + (k >> 1); col = (k & 1) * 16; }
            *(half8*)(smem + OFF_A + cg * APITCH_CG + row * APITCH_Y + col * 16) = (half8)(_Float16)0.f;
        }
    }

    // ---- P1: embedding gather + sum -> A_pad interior ----
    if (tid < NPIX) {
        const float* e0 = emb + c0 * 48;
        const float* e1 = emb + c1 * 48;
        int y = tid / 15, x = tid - y * 15;
        unsigned char* abase = smem + OFF_A + (y + 1) * APITCH_Y + (x + 1) * 16;
        #pragma unroll
        for (int g = 0; g < 6; g++) {
            f32x4 x0 = *(const f32x4*)(e0 + g * 8);
            f32x4 x1 = *(const f32x4*)(e0 + g * 8 + 4);
            f32x4 y0 = *(const f32x4*)(e1 + g * 8);
            f32x4 y1 = *(const f32x4*)(e1 + g * 8 + 4);
            f32x4 s0 = x0 + y0, s1 = x1 + y1;
            half2_t q0 = pkrtz(s0.x, s0.y), q1 = pkrtz(s0.z, s0.w);
            half2_t q2 = pkrtz(s1.x, s1.y), q3 = pkrtz(s1.z, s1.w);
            half8 hv = {q0[0], q0[1], q1[0], q1[1], q2[0], q2[1], q3[0], q3[1]};
            *(half8*)(abase + g * APITCH_CG) = hv;
        }
    }
    __syncthreads();

    // ---- P2: depthwise 3x3 via 5-px strips -> REGISTERS (A will be overwritten) ----
    auto compute_strip = [&](int t, half8* acc) {
        int cg = t / 45, rem = t - cg * 45;
        int y = rem / 3, s = rem - y * 3;
        int xs = s * 5;
        const unsigned char* wb = smem + OFF_WC + cg * 144;
        half8 wv[9];
        #pragma unroll
        for (int i = 0; i < 9; i++) wv[i] = *(const half8*)(wb + i * 16);
        half8 bias = *(const half8*)(smem + OFF_WCB + cg * 16);
        #pragma unroll
        for (int o = 0; o < 5; o++) acc[o] = bias;
        const unsigned char* ab = smem + OFF_A + cg * APITCH_CG + y * APITCH_Y + xs * 16;
        #pragma unroll
        for (int c = 0; c < 7; c++) {
            half8 v0 = *(const half8*)(ab + c * 16);
            half8 v1 = *(const half8*)(ab + APITCH_Y + c * 16);
            half8 v2 = *(const half8*)(ab + 2 * APITCH_Y + c * 16);
            #pragma unroll
            for (int o = 0; o < 5; o++) {
                int kx = c - o;
                if (kx >= 0 && kx <= 2) {
                    acc[o] = __builtin_elementwise_fma(v0, wv[kx],     acc[o]);
                    acc[o] = __builtin_elementwise_fma(v1, wv[3 + kx], acc[o]);
                    acc[o] = __builtin_elementwise_fma(v2, wv[6 + kx], acc[o]);
                }
            }
        }
    };
    auto write_strip = [&](int t, half8* acc) {
        int cg = t / 45, rem = t - cg * 45;
        int y = rem / 3, s = rem - y * 3;
        int xs = s * 5;
        unsigned char* xw = smem + OFF_X + (y * 15 + xs) * XPITCH + cg * 16;
        #pragma unroll
        for (int o = 0; o < 5; o++)
            *(half8*)(xw + o * XPITCH) = __builtin_elementwise_max(acc[o], (half8)(_Float16)0.f);
    };

    half8 acc1[5];
    compute_strip(tid, acc1);
    const int e = wave * 4 + lane;
    const bool has2 = (lane < 4) && (e < 14);
    half8 acc2[5];
    if (has2) compute_strip(256 + e, acc2);
    __syncthreads();     // all A reads done -> safe to overwrite with X

    // ---- P2b: write X (aliases dead A), zero PolA pads ----
    write_strip(tid, acc1);
    if (has2) write_strip(256 + e, acc2);
    if (tid < 128) {     // PolA_pad borders: 64 slots per cg
        int cg = tid >> 6, j = tid & 63;
        int row, col;
        if (j < 17)      { row = 0;  col = j; }
        else if (j < 34) { row = 16; col = j - 17; }
        else { int k = j - 34; row = 1 + (k >> 1); col = (k & 1) * 16; }
        *(half8*)(smem + OFF_POLA + cg * APITCH_CG + row * APITCH_Y + col * 16) = (half8)(_Float16)0.f;
    }

    // ---- head-weight conversion (small, register-light) ----
    const int n = lane & 15, q = lane >> 4;
    half8 af_p;
    {
        const float* wp = ppw_w + n * 16 + (q & 1) * 8;
        f32x4 w0 = *(const f32x4*)wp, w1 = *(const f32x4*)(wp + 4);
        half8 t = {(_Float16)w0.x, (_Float16)w0.y, (_Float16)w0.z, (_Float16)w0.w,
                   (_Float16)w1.x, (_Float16)w1.y, (_Float16)w1.z, (_Float16)w1.w};
        af_p = (q < 2) ? t : (half8)(_Float16)0.f;   // K zero-pad 16..31
    }
    f32x4 pb = *(const f32x4*)(ppw_b + q * 4);
    half2_t pfh[8];
    #pragma unroll
    for (int j = 0; j < 8; j++) pfh[j] = pkrtz(pf_w[2 * j], pf_w[2 * j + 1]);
    half8 af0, af1;
    {
        const float* wp = vpw_w + n * 32 + q * 8;
        f32x4 w0 = *(const f32x4*)wp, w1 = *(const f32x4*)(wp + 4);
        af0 = half8{(_Float16)w0.x, (_Float16)w0.y, (_Float16)w0.z, (_Float16)w0.w,
                    (_Float16)w1.x, (_Float16)w1.y, (_Float16)w1.z, (_Float16)w1.w};
        const float* wp2 = vpw_w + (16 + n) * 32 + q * 8;
        f32x4 v0 = *(const f32x4*)wp2, v1 = *(const f32x4*)(wp2 + 4);
        af1 = half8{(_Float16)v0.x, (_Float16)v0.y, (_Float16)v0.z, (_Float16)v0.w,
                    (_Float16)v1.x, (_Float16)v1.y, (_Float16)v1.z, (_Float16)v1.w};
    }
    f32x4 vb0 = *(const f32x4*)(vpw_b + q * 4);
    f32x4 vb1 = *(const f32x4*)(vpw_b + 16 + q * 4);
    __syncthreads();

    // ================= head split: no more block barriers =================
    if (wave < 3) {
        // ---------------- policy path (waves 0,1,2) ----------------
        const int cgp = lane & 1;
        half8 wvp[9];
        #pragma unroll
        for (int t = 0; t < 9; t++) wvp[t] = *(const half8*)(smem + OFF_WPD + cgp * 144 + t * 16);
        half8 biasp = *(const half8*)(smem + OFF_WPDB + cgp * 16);

        // ph3: 1x1 16->16 via MFMA; each wave computes every tile its ph4 rows need
        const int tlo = (wave == 0) ? 0 : ((wave == 1) ? 3 : 8);
        const int thi = (wave == 0) ? 6 : ((wave == 1) ? 11 : 15);
        const int cg3 = q >> 1;
        for (int t = tlo; t < thi; t++) {
            int p = t * 16 + n;
            half8 bf = *(const half8*)(smem + OFF_X + p * XPITCH + q * 16);
            f32x4 d = __builtin_amdgcn_mfma_f32_16x16x32_f16(af_p, bf, (f32x4)(0.f), 0, 0, 0);
            if (p < NPIX) {
                int y = p / 15, x = p - y * 15;
                half2_t lo = pkrtz(fmaxf(d.x + pb.x, 0.f), fmaxf(d.y + pb.y, 0.f));
                half2_t hi = pkrtz(fmaxf(d.z + pb.z, 0.f), fmaxf(d.w + pb.w, 0.f));
                half4_t hv = {lo[0], lo[1], hi[0], hi[1]};
                *(half4_t*)(smem + OFF_POLA + cg3 * APITCH_CG + (y + 1) * APITCH_Y + (x + 1) * 16 + (q & 1) * 8) = hv;
            }
        }
        wave_fence();

        // ph4+ph5 fused: dw 3x3 + bias + relu + dot(pf) + pair-sum + store
        const int px0 = wave * 75;
        for (int i = 0; i < 3; i++) {
            int idx = i * 64 + lane;
            if (idx < 150) {
                int px = px0 + (idx >> 1);
                int y = px / 15, x = px - y * 15;
                const unsigned char* pbse = smem + OFF_POLA + cgp * APITCH_CG + y * APITCH_Y + x * 16;
                half8 acc = biasp;
                #pragma unroll
                for (int ky = 0; ky < 3; ky++) {
                    acc = __builtin_elementwise_fma(*(const half8*)(pbse + ky * APITCH_Y),      wvp[ky * 3 + 0], acc);
                    acc = __builtin_elementwise_fma(*(const half8*)(pbse + ky * APITCH_Y + 16), wvp[ky * 3 + 1], acc);
                    acc = __builtin_elementwise_fma(*(const half8*)(pbse + ky * APITCH_Y + 32), wvp[ky * 3 + 2], acc);
                }
                acc = __builtin_elementwise_max(acc, (half8)(_Float16)0.f);
                float part = 0.f;
                part = __builtin_amdgcn_fdot2(half2_t{acc[0], acc[1]}, pfh[cgp * 4 + 0], part, false);
                part = __builtin_amdgcn_fdot2(half2_t{acc[2], acc[3]}, pfh[cgp * 4 + 1], part, false);
                part = __builtin_amdgcn_fdot2(half2_t{acc[4], acc[5]}, pfh[cgp * 4 + 2], part, false);
                part = __builtin_amdgcn_fdot2(half2_t{acc[6], acc[7]}, pfh[cgp * 4 + 3], part, false);
                float tot = part + __shfl_xor(part, 1, 64);
                if (cgp == 0) out[3 * batch + b * NPIX + px] = tot;
            }
        }
    } else {
        // ---------------- value path (wave 3, whole head in-wave) ----------------
        f32x4 a0 = {0.f, 0.f, 0.f, 0.f}, a1 = {0.f, 0.f, 0.f, 0.f};
        for (int t = 0; t < 15; t++) {
            int p = t * 16 + n;
            half8 bf = *(const half8*)(smem + OFF_X + p * XPITCH + 32 + q * 16);
            f32x4 d0 = __builtin_amdgcn_mfma_f32_16x16x32_f16(af0, bf, (f32x4)(0.f), 0, 0, 0);
            f32x4 d1 = __builtin_amdgcn_mfma_f32_16x16x32_f16(af1, bf, (f32x4)(0.f), 0, 0, 0);
            if (p < NPIX) {
                #pragma unroll
                for (int r = 0; r < 4; r++) {
                    a0[r] += fmaxf(d0[r] + vb0[r], 0.f);
                    a1[r] += fmaxf(d1[r] + vb1[r], 0.f);
                }
            }
        }
        #pragma unroll
        for (int s = 1; s < 16; s <<= 1) {
            #pragma unroll
            for (int r = 0; r < 4; r++) {
                a0[r] += __shfl_xor(a0[r], s, 64);
                a1[r] += __shfl_xor(a1[r], s, 64);
            }
        }
        if (n == 0) {
            *(f32x4*)(smem + OFF_SV + q * 16)      = a0 * (1.f / 225.f);
            *(f32x4*)(smem + OFF_SV + 64 + q * 16) = a1 * (1.f / 225.f);
        }
        wave_fence();

        // FC weights read directly from global (L2-resident) -- NO register prefetch
        const int o = lane & 31;
        float acc1f = vl1_b[o];
        #pragma unroll
        for (int g = 0; g < 8; g++) {
            f32x4 sv = *(const f32x4*)(smem + OFF_SV + g * 16);
            f32x4 w4 = *(const f32x4*)(vl1_w + o * 32 + g * 4);
            acc1f += sv.x * w4.x + sv.y * w4.y + sv.z * w4.z + sv.w * w4.w;
        }
        acc1f = fmaxf(acc1f, 0.f);
        if (lane < 32) *(float*)(smem + OFF_H1 + o * 4) = acc1f;
        wave_fence();

        float acc2f = vl2_b[o];
        #pragma unroll
        for (int g = 0; g < 8; g++) {
            f32x4 hv = *(const f32x4*)(smem + OFF_H1 + g * 16);
            f32x4 w4 = *(const f32x4*)(vl2_w + o * 32 + g * 4);
            acc2f += hv.x * w4.x + hv.y * w4.y + hv.z * w4.z + hv.w * w4.w;
        }
        acc2f = fmaxf(acc2f, 0.f);
        if (lane < 32) *(float*)(smem + OFF_H2 + o * 4) = acc2f;
        wave_fence();

        if (lane < 3) {
            float acc3f = vf_b[lane];
            #pragma unroll
            for (int g = 0; g < 8; g++) {
                f32x4 hv = *(const f32x4*)(smem + OFF_H2 + g * 16);
                f32x4 w4 = *(const f32x4*)(vf_w + lane * 32 + g * 4);
                acc3f += hv.x * w4.x + hv.y * w4.y + hv.z * w4.z + hv.w * w4.w;
            }
            out[b * 3 + lane] = acc3f;
        }
    }
}

extern "C" void kernel_launch(void* const* d_in, const int* in_sizes, int n_in,
                              void* d_out, int out_size, void* d_ws, size_t ws_size,
                              hipStream_t stream) {
    const float* emb    = (const float*)d_in[0];
    const float* conv_w = (const float*)d_in[1];
    const float* conv_b = (const float*)d_in[2];
    const float* ppw_w  = (const float*)d_in[3];
    const float* ppw_b  = (const float*)d_in[4];
    const float* pdw_w  = (const float*)d_in[5];
    const float* pdw_b  = (const float*)d_in[6];
    const float* pf_w   = (const float*)d_in[7];
    const float* vpw_w  = (const float*)d_in[8];
    const float* vpw_b  = (const float*)d_in[9];
    const float* vl1_w  = (const float*)d_in[10];
    const float* vl1_b  = (const float*)d_in[11];
    const float* vl2_w  = (const float*)d_in[12];
    const float* vl2_b  = (const float*)d_in[13];
    const float* vf_w   = (const float*)d_in[14];
    const float* vf_b   = (const float*)d_in[15];
    const int* sparse   = (const int*)d_in[16];
    const int* board    = (const int*)d_in[17];
    float* out = (float*)d_out;

    int batch = in_sizes[16] / 2700;  // 4096
    patnet_kernel<<<batch, NT, 0, stream>>>(
        emb, conv_w, conv_b, ppw_w, ppw_b, pdw_w, pdw_b, pf_w,
        vpw_w, vpw_b, vl1_w, vl1_b, vl2_w, vl2_b, vf_w, vf_b,
        sparse, board, out, batch);
}

// Round 10
// 192.804 us; speedup vs baseline: 1.2728x; 1.2728x over previous
//
#include <hip/hip_runtime.h>
#include <hip/hip_fp16.h>

typedef _Float16 half8  __attribute__((ext_vector_type(8)));
typedef _Float16 half4_t __attribute__((ext_vector_type(4)));
typedef _Float16 half2_t __attribute__((ext_vector_type(2)));
typedef float f32x4 __attribute__((ext_vector_type(4)));

namespace {
constexpr int NT = 256;
constexpr int NPIX = 225;
constexpr int PCODE_C = 2380;

// A_pad[6][17][17] half8 slots: row pitch 272 B, cg pitch 4624 B
constexpr int APITCH_Y  = 272;
constexpr int APITCH_CG = 4624;
constexpr int XPITCH = 112;   // X row pitch (48 f16 data + pad)

// ---- LDS layout (byte offsets) ----
constexpr int OFF_A     = 0;       // A_pad 27744; ALIASED by X (240*112=26880) after barrier 2
constexpr int OFF_X     = 0;
constexpr int OFF_POLA  = 26880;   // PolA_pad[2][17][17] slots = 9248 -> ends 36128
constexpr int OFF_WC    = 36128;   // dw conv w  f16 [6][9][8]  = 864
constexpr int OFF_WCB   = 36992;   // dw conv b  f16 [6][8]     = 96
constexpr int OFF_WPD   = 37088;   // pol dw w   f16 [2][9][8]  = 288
constexpr int OFF_WPDB  = 37376;   // pol dw b   f16 [2][8]     = 32
constexpr int OFF_SV    = 37408;   // f32[32] = 128
constexpr int OFF_H1    = 37536;   // f32[32] = 128
constexpr int OFF_H2    = 37664;   // f32[32] = 128
constexpr int SMEM_BYTES = 37792;  // 4 blocks/CU by LDS (4*37792 = 151168 < 163840)
}

__device__ __forceinline__ half2_t pkrtz(float a, float b) {
    return __builtin_bit_cast(half2_t, __builtin_amdgcn_cvt_pkrtz(a, b));
}
__device__ __forceinline__ void wave_fence() {
    asm volatile("s_waitcnt lgkmcnt(0)" ::: "memory");
}

// NOTE: (NT,4) forces a 64-VGPR arch split with MFMA -> 300+ MB scratch spill
// (measured R8/R9). (NT,3) gives ~170 cap, natural alloc ~110, no spill; HW
// still schedules 4 blocks/CU when VGPR<=128 and LDS<=40KB.
__global__ __launch_bounds__(NT, 3) void patnet_kernel(
    const float* __restrict__ emb,
    const float* __restrict__ conv_w, const float* __restrict__ conv_b,
    const float* __restrict__ ppw_w,  const float* __restrict__ ppw_b,
    const float* __restrict__ pdw_w,  const float* __restrict__ pdw_b,
    const float* __restrict__ pf_w,
    const float* __restrict__ vpw_w,  const float* __restrict__ vpw_b,
    const float* __restrict__ vl1_w,  const float* __restrict__ vl1_b,
    const float* __restrict__ vl2_w,  const float* __restrict__ vl2_b,
    const float* __restrict__ vf_w,   const float* __restrict__ vf_b,
    const int* __restrict__ sparse,   const int* __restrict__ board,
    float* __restrict__ out, int batch)
{
    __shared__ __align__(16) unsigned char smem[SMEM_BYTES];
    const int tid  = threadIdx.x;
    const int b    = blockIdx.x;
    const int lane = tid & 63;
    const int wave = tid >> 6;

    // ---- issue code loads first (deep prefetch) ----
    int c0 = 0, c1 = 0;
    if (tid < NPIX) {
        int s10 = sparse[b * 2700 + 10 * NPIX + tid];
        int s11 = sparse[b * 2700 + 11 * NPIX + tid];
        int b0  = board[b * 450 + tid];
        int b1  = board[b * 450 + NPIX + tid];
        c0 = (b0 > 0) ? PCODE_C : s10;
        c1 = ((b1 > 0) ? PCODE_C : s11) + (PCODE_C + 1);
    }

    // ---- P0: stage depthwise weight tables (transposed) + zero A pads ----
    {
        _Float16* Wc   = (_Float16*)(smem + OFF_WC);
        _Float16* Wcb  = (_Float16*)(smem + OFF_WCB);
        _Float16* Wpd  = (_Float16*)(smem + OFF_WPD);
        _Float16* Wpdb = (_Float16*)(smem + OFF_WPDB);
        for (int i = tid; i < 432; i += NT) {     // Wc[cg][tap][j] = conv_w[(cg*8+j)*9+tap]
            int cg = i / 72, rem = i - cg * 72;
            int t = rem >> 3, j = rem & 7;
            Wc[i] = (_Float16)conv_w[(cg * 8 + j) * 9 + t];
        }
        for (int i = tid; i < 48; i += NT) Wcb[i] = (_Float16)conv_b[i];
        for (int i = tid; i < 144; i += NT) {
            int cg = i / 72, rem = i - cg * 72;
            int t = rem >> 3, j = rem & 7;
            Wpd[i] = (_Float16)pdw_w[(cg * 8 + j) * 9 + t];
        }
        for (int i = tid; i < 16; i += NT) Wpdb[i] = (_Float16)pdw_b[i];
        // zero A_pad borders: 64 slots per cg
        for (int i = tid; i < 384; i += NT) {
            int cg = i >> 6, j = i & 63;
            int row, col;
            if (j < 17)      { row = 0;  col = j; }
            else if (j < 34) { row = 16; col = j - 17; }
            else { int k = j - 34; row = 1 + (k >> 1); col = (k & 1) * 16; }
            *(half8*)(smem + OFF_A + cg * APITCH_CG + row * APITCH_Y + col * 16) = (half8)(_Float16)0.f;
        }
    }

    // ---- P1: embedding gather + sum -> A_pad interior ----
    if (tid < NPIX) {
        const float* e0 = emb + c0 * 48;
        const float* e1 = emb + c1 * 48;
        int y = tid / 15, x = tid - y * 15;
        unsigned char* abase = smem + OFF_A + (y + 1) * APITCH_Y + (x + 1) * 16;
        #pragma unroll
        for (int g = 0; g < 6; g++) {
            f32x4 x0 = *(const f32x4*)(e0 + g * 8);
            f32x4 x1 = *(const f32x4*)(e0 + g * 8 + 4);
            f32x4 y0 = *(const f32x4*)(e1 + g * 8);
            f32x4 y1 = *(const f32x4*)(e1 + g * 8 + 4);
            f32x4 s0 = x0 + y0, s1 = x1 + y1;
            half2_t q0 = pkrtz(s0.x, s0.y), q1 = pkrtz(s0.z, s0.w);
            half2_t q2 = pkrtz(s1.x, s1.y), q3 = pkrtz(s1.z, s1.w);
            half8 hv = {q0[0], q0[1], q1[0], q1[1], q2[0], q2[1], q3[0], q3[1]};
            *(half8*)(abase + g * APITCH_CG) = hv;
        }
    }
    __syncthreads();

    // ---- P2: depthwise 3x3 via 5-px strips -> REGISTERS (A will be overwritten) ----
    auto compute_strip = [&](int t, half8* acc) {
        int cg = t / 45, rem = t - cg * 45;
        int y = rem / 3, s = rem - y * 3;
        int xs = s * 5;
        const unsigned char* wb = smem + OFF_WC + cg * 144;
        half8 wv[9];
        #pragma unroll
        for (int i = 0; i < 9; i++) wv[i] = *(const half8*)(wb + i * 16);
        half8 bias = *(const half8*)(smem + OFF_WCB + cg * 16);
        #pragma unroll
        for (int o = 0; o < 5; o++) acc[o] = bias;
        const unsigned char* ab = smem + OFF_A + cg * APITCH_CG + y * APITCH_Y + xs * 16;
        #pragma unroll
        for (int c = 0; c < 7; c++) {
            half8 v0 = *(const half8*)(ab + c * 16);
            half8 v1 = *(const half8*)(ab + APITCH_Y + c * 16);
            half8 v2 = *(const half8*)(ab + 2 * APITCH_Y + c * 16);
            #pragma unroll
            for (int o = 0; o < 5; o++) {
                int kx = c - o;
                if (kx >= 0 && kx <= 2) {
                    acc[o] = __builtin_elementwise_fma(v0, wv[kx],     acc[o]);
                    acc[o] = __builtin_elementwise_fma(v1, wv[3 + kx], acc[o]);
                    acc[o] = __builtin_elementwise_fma(v2, wv[6 + kx], acc[o]);
                }
            }
        }
    };
    auto write_strip = [&](int t, half8* acc) {
        int cg = t / 45, rem = t - cg * 45;
        int y = rem / 3, s = rem - y * 3;
        int xs = s * 5;
        unsigned char* xw = smem + OFF_X + (y * 15 + xs) * XPITCH + cg * 16;
        #pragma unroll
        for (int o = 0; o < 5; o++)
            *(half8*)(xw + o * XPITCH) = __builtin_elementwise_max(acc[o], (half8)(_Float16)0.f);
    };

    half8 acc1[5];
    compute_strip(tid, acc1);
    const int e = wave * 4 + lane;
    const bool has2 = (lane < 4) && (e < 14);
    half8 acc2[5];
    if (has2) compute_strip(256 + e, acc2);
    __syncthreads();     // all A reads done -> safe to overwrite with X

    // ---- P2b: write X (aliases dead A), zero PolA pads ----
    write_strip(tid, acc1);
    if (has2) write_strip(256 + e, acc2);
    if (tid < 128) {     // PolA_pad borders: 64 slots per cg
        int cg = tid >> 6, j = tid & 63;
        int row, col;
        if (j < 17)      { row = 0;  col = j; }
        else if (j < 34) { row = 16; col = j - 17; }
        else { int k = j - 34; row = 1 + (k >> 1); col = (k & 1) * 16; }
        *(half8*)(smem + OFF_POLA + cg * APITCH_CG + row * APITCH_Y + col * 16) = (half8)(_Float16)0.f;
    }

    // ---- head-weight conversion (small, register-light) ----
    const int n = lane & 15, q = lane >> 4;
    half8 af_p;
    {
        const float* wp = ppw_w + n * 16 + (q & 1) * 8;
        f32x4 w0 = *(const f32x4*)wp, w1 = *(const f32x4*)(wp + 4);
        half8 t = {(_Float16)w0.x, (_Float16)w0.y, (_Float16)w0.z, (_Float16)w0.w,
                   (_Float16)w1.x, (_Float16)w1.y, (_Float16)w1.z, (_Float16)w1.w};
        af_p = (q < 2) ? t : (half8)(_Float16)0.f;   // K zero-pad 16..31
    }
    f32x4 pb = *(const f32x4*)(ppw_b + q * 4);
    half2_t pfh[8];
    #pragma unroll
    for (int j = 0; j < 8; j++) pfh[j] = pkrtz(pf_w[2 * j], pf_w[2 * j + 1]);
    half8 af0, af1;
    {
        const float* wp = vpw_w + n * 32 + q * 8;
        f32x4 w0 = *(const f32x4*)wp, w1 = *(const f32x4*)(wp + 4);
        af0 = half8{(_Float16)w0.x, (_Float16)w0.y, (_Float16)w0.z, (_Float16)w0.w,
                    (_Float16)w1.x, (_Float16)w1.y, (_Float16)w1.z, (_Float16)w1.w};
        const float* wp2 = vpw_w + (16 + n) * 32 + q * 8;
        f32x4 v0 = *(const f32x4*)wp2, v1 = *(const f32x4*)(wp2 + 4);
        af1 = half8{(_Float16)v0.x, (_Float16)v0.y, (_Float16)v0.z, (_Float16)v0.w,
                    (_Float16)v1.x, (_Float16)v1.y, (_Float16)v1.z, (_Float16)v1.w};
    }
    f32x4 vb0 = *(const f32x4*)(vpw_b + q * 4);
    f32x4 vb1 = *(const f32x4*)(vpw_b + 16 + q * 4);
    __syncthreads();

    // ================= head split: no more block barriers =================
    if (wave < 3) {
        // ---------------- policy path (waves 0,1,2) ----------------
        const int cgp = lane & 1;
        half8 wvp[9];
        #pragma unroll
        for (int t = 0; t < 9; t++) wvp[t] = *(const half8*)(smem + OFF_WPD + cgp * 144 + t * 16);
        half8 biasp = *(const half8*)(smem + OFF_WPDB + cgp * 16);

        // ph3: 1x1 16->16 via MFMA; each wave computes every tile its ph4 rows need
        const int tlo = (wave == 0) ? 0 : ((wave == 1) ? 3 : 8);
        const int thi = (wave == 0) ? 6 : ((wave == 1) ? 11 : 15);
        const int cg3 = q >> 1;
        for (int t = tlo; t < thi; t++) {
            int p = t * 16 + n;
            half8 bf = *(const half8*)(smem + OFF_X + p * XPITCH + q * 16);
            f32x4 d = __builtin_amdgcn_mfma_f32_16x16x32_f16(af_p, bf, (f32x4)(0.f), 0, 0, 0);
            if (p < NPIX) {
                int y = p / 15, x = p - y * 15;
                half2_t lo = pkrtz(fmaxf(d.x + pb.x, 0.f), fmaxf(d.y + pb.y, 0.f));
                half2_t hi = pkrtz(fmaxf(d.z + pb.z, 0.f), fmaxf(d.w + pb.w, 0.f));
                half4_t hv = {lo[0], lo[1], hi[0], hi[1]};
                *(half4_t*)(smem + OFF_POLA + cg3 * APITCH_CG + (y + 1) * APITCH_Y + (x + 1) * 16 + (q & 1) * 8) = hv;
            }
        }
        wave_fence();

        // ph4+ph5 fused: dw 3x3 + bias + relu + dot(pf) + pair-sum + store
        const int px0 = wave * 75;
        for (int i = 0; i < 3; i++) {
            int idx = i * 64 + lane;
            if (idx < 150) {
                int px = px0 + (idx >> 1);
                int y = px / 15, x = px - y * 15;
                const unsigned char* pbse = smem + OFF_POLA + cgp * APITCH_CG + y * APITCH_Y + x * 16;
                half8 acc = biasp;
                #pragma unroll
                for (int ky = 0; ky < 3; ky++) {
                    acc = __builtin_elementwise_fma(*(const half8*)(pbse + ky * APITCH_Y),      wvp[ky * 3 + 0], acc);
                    acc = __builtin_elementwise_fma(*(const half8*)(pbse + ky * APITCH_Y + 16), wvp[ky * 3 + 1], acc);
                    acc = __builtin_elementwise_fma(*(const half8*)(pbse + ky * APITCH_Y + 32), wvp[ky * 3 + 2], acc);
                }
                acc = __builtin_elementwise_max(acc, (half8)(_Float16)0.f);
                float part = 0.f;
                part = __builtin_amdgcn_fdot2(half2_t{acc[0], acc[1]}, pfh[cgp * 4 + 0], part, false);
                part = __builtin_amdgcn_fdot2(half2_t{acc[2], acc[3]}, pfh[cgp * 4 + 1], part, false);
                part = __builtin_amdgcn_fdot2(half2_t{acc[4], acc[5]}, pfh[cgp * 4 + 2], part, false);
                part = __builtin_amdgcn_fdot2(half2_t{acc[6], acc[7]}, pfh[cgp * 4 + 3], part, false);
                float tot = part + __shfl_xor(part, 1, 64);
                if (cgp == 0) out[3 * batch + b * NPIX + px] = tot;
            }
        }
    } else {
        // ---------------- value path (wave 3, whole head in-wave) ----------------
        f32x4 a0 = {0.f, 0.f, 0.f, 0.f}, a1 = {0.f, 0.f, 0.f, 0.f};
        for (int t = 0; t < 15; t++) {
            int p = t * 16 + n;
            half8 bf = *(const half8*)(smem + OFF_X + p * XPITCH + 32 + q * 16);
            f32x4 d0 = __builtin_amdgcn_mfma_f32_16x16x32_f16(af0, bf, (f32x4)(0.f), 0, 0, 0);
            f32x4 d1 = __builtin_amdgcn_mfma_f32_16x16x32_f16(af1, bf, (f32x4)(0.f), 0, 0, 0);
            if (p < NPIX) {
                #pragma unroll
                for (int r = 0; r < 4; r++) {
                    a0[r] += fmaxf(d0[r] + vb0[r], 0.f);
                    a1[r] += fmaxf(d1[r] + vb1[r], 0.f);
                }
            }
        }
        #pragma unroll
        for (int s = 1; s < 16; s <<= 1) {
            #pragma unroll
            for (int r = 0; r < 4; r++) {
                a0[r] += __shfl_xor(a0[r], s, 64);
                a1[r] += __shfl_xor(a1[r], s, 64);
            }
        }
        if (n == 0) {
            *(f32x4*)(smem + OFF_SV + q * 16)      = a0 * (1.f / 225.f);
            *(f32x4*)(smem + OFF_SV + 64 + q * 16) = a1 * (1.f / 225.f);
        }
        wave_fence();

        // FC weights read directly from global (L2-resident) -- no register prefetch
        const int o = lane & 31;
        float acc1f = vl1_b[o];
        #pragma unroll
        for (int g = 0; g < 8; g++) {
            f32x4 sv = *(const f32x4*)(smem + OFF_SV + g * 16);
            f32x4 w4 = *(const f32x4*)(vl1_w + o * 32 + g * 4);
            acc1f += sv.x * w4.x + sv.y * w4.y + sv.z * w4.z + sv.w * w4.w;
        }
        acc1f = fmaxf(acc1f, 0.f);
        if (lane < 32) *(float*)(smem + OFF_H1 + o * 4) = acc1f;
        wave_fence();

        float acc2f = vl2_b[o];
        #pragma unroll
        for (int g = 0; g < 8; g++) {
            f32x4 hv = *(const f32x4*)(smem + OFF_H1 + g * 16);
            f32x4 w4 = *(const f32x4*)(vl2_w + o * 32 + g * 4);
            acc2f += hv.x * w4.x + hv.y * w4.y + hv.z * w4.z + hv.w * w4.w;
        }
        acc2f = fmaxf(acc2f, 0.f);
        if (lane < 32) *(float*)(smem + OFF_H2 + o * 4) = acc2f;
        wave_fence();

        if (lane < 3) {
            float acc3f = vf_b[lane];
            #pragma unroll
            for (int g = 0; g < 8; g++) {
                f32x4 hv = *(const f32x4*)(smem + OFF_H2 + g * 16);
                f32x4 w4 = *(const f32x4*)(vf_w + lane * 32 + g * 4);
                acc3f += hv.x * w4.x + hv.y * w4.y + hv.z * w4.z + hv.w * w4.w;
            }
            out[b * 3 + lane] = acc3f;
        }
    }
}

extern "C" void kernel_launch(void* const* d_in, const int* in_sizes, int n_in,
                              void* d_out, int out_size, void* d_ws, size_t ws_size,
                              hipStream_t stream) {
    const float* emb    = (const float*)d_in[0];
    const float* conv_w = (const float*)d_in[1];
    const float* conv_b = (const float*)d_in[2];
    const float* ppw_w  = (const float*)d_in[3];
    const float* ppw_b  = (const float*)d_in[4];
    const float* pdw_w  = (const float*)d_in[5];
    const float* pdw_b  = (const float*)d_in[6];
    const float* pf_w   = (const float*)d_in[7];
    const float* vpw_w  = (const float*)d_in[8];
    const float* vpw_b  = (const float*)d_in[9];
    const float* vl1_w  = (const float*)d_in[10];
    const float* vl1_b  = (const float*)d_in[11];
    const float* vl2_w  = (const float*)d_in[12];
    const float* vl2_b  = (const float*)d_in[13];
    const float* vf_w   = (const float*)d_in[14];
    const float* vf_b   = (const float*)d_in[15];
    const int* sparse   = (const int*)d_in[16];
    const int* board    = (const int*)d_in[17];
    float* out = (float*)d_out;

    int batch = in_sizes[16] / 2700;  // 4096
    patnet_kernel<<<batch, NT, 0, stream>>>(
        emb, conv_w, conv_b, ppw_w, ppw_b, pdw_w, pdw_b, pf_w,
        vpw_w, vpw_b, vl1_w, vl1_b, vl2_w, vl2_b, vf_w, vf_b,
        sparse, board, out, batch);
}

// Round 11
// 183.648 us; speedup vs baseline: 1.3362x; 1.0499x over previous
//
#include <hip/hip_runtime.h>
#include <hip/hip_fp16.h>

typedef _Float16 half8  __attribute__((ext_vector_type(8)));
typedef _Float16 half4_t __attribute__((ext_vector_type(4)));
typedef _Float16 half2_t __attribute__((ext_vector_type(2)));
typedef float f32x4 __attribute__((ext_vector_type(4)));

namespace {
constexpr int NT = 256;
constexpr int NPIX = 225;
constexpr int PCODE_C = 2380;

// A_pad[6][17][17] half8 slots: row pitch 272 B, cg pitch 4624 B
constexpr int APITCH_Y  = 272;
constexpr int APITCH_CG = 4624;
constexpr int XPITCH = 112;   // X row pitch (48 f16 data + pad)

// ---- LDS layout (byte offsets) ----
constexpr int OFF_A     = 0;       // A_pad 27744; ALIASED by X (240*112=26880) after barrier 2
constexpr int OFF_X     = 0;
constexpr int OFF_POLA  = 26880;   // PolA_pad[2][17][17] slots = 9248 -> ends 36128 (overlaps dead A tail)
constexpr int OFF_WC    = 36128;   // dw conv w  f16 [6][9][8]  = 864
constexpr int OFF_WCB   = 36992;   // dw conv b  f16 [6][8]     = 96
constexpr int OFF_WPD   = 37088;   // pol dw w   f16 [2][9][8]  = 288
constexpr int OFF_WPDB  = 37376;   // pol dw b   f16 [2][8]     = 32
constexpr int OFF_SV    = 37408;   // f32[32] = 128
constexpr int OFF_H1    = 37536;   // f32[32] = 128
constexpr int OFF_H2    = 37664;   // f32[32] = 128
constexpr int OFF_STAGE = 37792;   // leftover-strip staging: 14*5 half8 = 1120
constexpr int SMEM_BYTES = 38912;  // 4 blocks/CU by LDS (4*38912 = 155648 < 163840)
}

__device__ __forceinline__ half2_t pkrtz(float a, float b) {
    return __builtin_bit_cast(half2_t, __builtin_amdgcn_cvt_pkrtz(a, b));
}
__device__ __forceinline__ void wave_fence() {
    asm volatile("s_waitcnt lgkmcnt(0)" ::: "memory");
}

// 5-px strip result: named members only -- NO local arrays cross the barrier.
// (R8-R10 lesson: half8 acc[5] passed by pointer across a barrier defeats SROA
// -> stack/scratch -> 300+/23 MB spill traffic. Named struct by value SROAs.)
struct S5 { half8 a, b, c, d, e; };

__device__ __forceinline__ half8 fma3(half8 v0, half8 v1, half8 v2,
                                      half8 w0, half8 w1, half8 w2, half8 acc) {
    acc = __builtin_elementwise_fma(v0, w0, acc);
    acc = __builtin_elementwise_fma(v1, w1, acc);
    acc = __builtin_elementwise_fma(v2, w2, acc);
    return acc;
}

__device__ __forceinline__ S5 strip_compute(const unsigned char* smem, int t) {
    int cg = t / 45, rem = t - cg * 45;
    int y = rem / 3, s = rem - y * 3;
    int xs = s * 5;
    const unsigned char* wb = smem + OFF_WC + cg * 144;
    half8 W0 = *(const half8*)(wb);       half8 W1 = *(const half8*)(wb + 16);
    half8 W2 = *(const half8*)(wb + 32);  half8 W3 = *(const half8*)(wb + 48);
    half8 W4 = *(const half8*)(wb + 64);  half8 W5 = *(const half8*)(wb + 80);
    half8 W6 = *(const half8*)(wb + 96);  half8 W7 = *(const half8*)(wb + 112);
    half8 W8 = *(const half8*)(wb + 128);
    half8 bias = *(const half8*)(smem + OFF_WCB + cg * 16);
    S5 r = {bias, bias, bias, bias, bias};
    const unsigned char* ab = smem + OFF_A + cg * APITCH_CG + y * APITCH_Y + xs * 16;
    #define LOADCOL(cidx, v0, v1, v2) \
        half8 v0 = *(const half8*)(ab + (cidx) * 16); \
        half8 v1 = *(const half8*)(ab + APITCH_Y + (cidx) * 16); \
        half8 v2 = *(const half8*)(ab + 2 * APITCH_Y + (cidx) * 16);
    { LOADCOL(0, u0, u1, u2)
      r.a = fma3(u0, u1, u2, W0, W3, W6, r.a); }
    { LOADCOL(1, u0, u1, u2)
      r.a = fma3(u0, u1, u2, W1, W4, W7, r.a);
      r.b = fma3(u0, u1, u2, W0, W3, W6, r.b); }
    { LOADCOL(2, u0, u1, u2)
      r.a = fma3(u0, u1, u2, W2, W5, W8, r.a);
      r.b = fma3(u0, u1, u2, W1, W4, W7, r.b);
      r.c = fma3(u0, u1, u2, W0, W3, W6, r.c); }
    { LOADCOL(3, u0, u1, u2)
      r.b = fma3(u0, u1, u2, W2, W5, W8, r.b);
      r.c = fma3(u0, u1, u2, W1, W4, W7, r.c);
      r.d = fma3(u0, u1, u2, W0, W3, W6, r.d); }
    { LOADCOL(4, u0, u1, u2)
      r.c = fma3(u0, u1, u2, W2, W5, W8, r.c);
      r.d = fma3(u0, u1, u2, W1, W4, W7, r.d);
      r.e = fma3(u0, u1, u2, W0, W3, W6, r.e); }
    { LOADCOL(5, u0, u1, u2)
      r.d = fma3(u0, u1, u2, W2, W5, W8, r.d);
      r.e = fma3(u0, u1, u2, W1, W4, W7, r.e); }
    { LOADCOL(6, u0, u1, u2)
      r.e = fma3(u0, u1, u2, W2, W5, W8, r.e); }
    #undef LOADCOL
    return r;
}

__global__ __launch_bounds__(NT, 3) void patnet_kernel(
    const float* __restrict__ emb,
    const float* __restrict__ conv_w, const float* __restrict__ conv_b,
    const float* __restrict__ ppw_w,  const float* __restrict__ ppw_b,
    const float* __restrict__ pdw_w,  const float* __restrict__ pdw_b,
    const float* __restrict__ pf_w,
    const float* __restrict__ vpw_w,  const float* __restrict__ vpw_b,
    const float* __restrict__ vl1_w,  const float* __restrict__ vl1_b,
    const float* __restrict__ vl2_w,  const float* __restrict__ vl2_b,
    const float* __restrict__ vf_w,   const float* __restrict__ vf_b,
    const int* __restrict__ sparse,   const int* __restrict__ board,
    float* __restrict__ out, int batch)
{
    __shared__ __align__(16) unsigned char smem[SMEM_BYTES];
    const int tid  = threadIdx.x;
    const int b    = blockIdx.x;
    const int lane = tid & 63;
    const int wave = tid >> 6;

    // ---- issue code loads first (deep prefetch) ----
    int c0 = 0, c1 = 0;
    if (tid < NPIX) {
        int s10 = sparse[b * 2700 + 10 * NPIX + tid];
        int s11 = sparse[b * 2700 + 11 * NPIX + tid];
        int b0  = board[b * 450 + tid];
        int b1  = board[b * 450 + NPIX + tid];
        c0 = (b0 > 0) ? PCODE_C : s10;
        c1 = ((b1 > 0) ? PCODE_C : s11) + (PCODE_C + 1);
    }

    // ---- P0: stage depthwise weight tables (transposed) + zero A pads ----
    {
        _Float16* Wc   = (_Float16*)(smem + OFF_WC);
        _Float16* Wcb  = (_Float16*)(smem + OFF_WCB);
        _Float16* Wpd  = (_Float16*)(smem + OFF_WPD);
        _Float16* Wpdb = (_Float16*)(smem + OFF_WPDB);
        for (int i = tid; i < 432; i += NT) {     // Wc[cg][tap][j] = conv_w[(cg*8+j)*9+tap]
            int cg = i / 72, rem = i - cg * 72;
            int t = rem >> 3, j = rem & 7;
            Wc[i] = (_Float16)conv_w[(cg * 8 + j) * 9 + t];
        }
        for (int i = tid; i < 48; i += NT) Wcb[i] = (_Float16)conv_b[i];
        for (int i = tid; i < 144; i += NT) {
            int cg = i / 72, rem = i - cg * 72;
            int t = rem >> 3, j = rem & 7;
            Wpd[i] = (_Float16)pdw_w[(cg * 8 + j) * 9 + t];
        }
        for (int i = tid; i < 16; i += NT) Wpdb[i] = (_Float16)pdw_b[i];
        // zero A_pad borders: 64 slots per cg
        for (int i = tid; i < 384; i += NT) {
            int cg = i >> 6, j = i & 63;
            int row, col;
            if (j < 17)      { row = 0;  col = j; }
            else if (j < 34) { row = 16; col = j - 17; }
            else { int k = j - 34; row = 1 + (k >> 1); col = (k & 1) * 16; }
            *(half8*)(smem + OFF_A + cg * APITCH_CG + row * APITCH_Y + col * 16) = (half8)(_Float16)0.f;
        }
    }

    // ---- P1: embedding gather + sum -> A_pad interior ----
    if (tid < NPIX) {
        const float* e0 = emb + c0 * 48;
        const float* e1 = emb + c1 * 48;
        int y = tid / 15, x = tid - y * 15;
        unsigned char* abase = smem + OFF_A + (y + 1) * APITCH_Y + (x + 1) * 16;
        #pragma unroll
        for (int g = 0; g < 6; g++) {
            f32x4 x0 = *(const f32x4*)(e0 + g * 8);
            f32x4 x1 = *(const f32x4*)(e0 + g * 8 + 4);
            f32x4 y0 = *(const f32x4*)(e1 + g * 8);
            f32x4 y1 = *(const f32x4*)(e1 + g * 8 + 4);
            f32x4 s0 = x0 + y0, s1 = x1 + y1;
            half2_t q0 = pkrtz(s0.x, s0.y), q1 = pkrtz(s0.z, s0.w);
            half2_t q2 = pkrtz(s1.x, s1.y), q3 = pkrtz(s1.z, s1.w);
            half8 hv = {q0[0], q0[1], q1[0], q1[1], q2[0], q2[1], q3[0], q3[1]};
            *(half8*)(abase + g * APITCH_CG) = hv;
        }
    }
    __syncthreads();

    // ---- P2: depthwise 3x3 via 5-px strips -> named registers (A overwritten later) ----
    S5 sr = strip_compute(smem, tid);
    {   // leftover strips 256..269: compute now, stage to LDS (not A!), copy after barrier
        int e = wave * 4 + lane;
        if (lane < 4 && e < 14) {
            S5 lr = strip_compute(smem, 256 + e);
            unsigned char* st = smem + OFF_STAGE + e * 80;
            *(half8*)(st)      = lr.a;
            *(half8*)(st + 16) = lr.b;
            *(half8*)(st + 32) = lr.c;
            *(half8*)(st + 48) = lr.d;
            *(half8*)(st + 64) = lr.e;
        }
    }
    __syncthreads();     // all A reads done -> safe to overwrite with X

    // ---- P2b: write X (aliases dead A), copy staged strips, zero PolA pads ----
    {
        int t = tid;
        int cg = t / 45, rem = t - cg * 45;
        int y = rem / 3, s = rem - y * 3;
        int xs = s * 5;
        unsigned char* xw = smem + OFF_X + (y * 15 + xs) * XPITCH + cg * 16;
        *(half8*)(xw)              = __builtin_elementwise_max(sr.a, (half8)(_Float16)0.f);
        *(half8*)(xw + XPITCH)     = __builtin_elementwise_max(sr.b, (half8)(_Float16)0.f);
        *(half8*)(xw + 2 * XPITCH) = __builtin_elementwise_max(sr.c, (half8)(_Float16)0.f);
        *(half8*)(xw + 3 * XPITCH) = __builtin_elementwise_max(sr.d, (half8)(_Float16)0.f);
        *(half8*)(xw + 4 * XPITCH) = __builtin_elementwise_max(sr.e, (half8)(_Float16)0.f);
    }
    if (tid < 70) {      // staged leftover strips -> X (t = 256 + tid/5, o = tid%5)
        int e = tid / 5, o = tid - e * 5;
        int t = 256 + e;
        int cg = t / 45, rem = t - cg * 45;
        int y = rem / 3, s = rem - y * 3;
        int xs = s * 5 + o;
        half8 v = *(const half8*)(smem + OFF_STAGE + tid * 16);
        *(half8*)(smem + OFF_X + (y * 15 + xs) * XPITCH + cg * 16) =
            __builtin_elementwise_max(v, (half8)(_Float16)0.f);
    }
    if (tid < 128) {     // PolA_pad borders: 64 slots per cg
        int cg = tid >> 6, j = tid & 63;
        int row, col;
        if (j < 17)      { row = 0;  col = j; }
        else if (j < 34) { row = 16; col = j - 17; }
        else { int k = j - 34; row = 1 + (k >> 1); col = (k & 1) * 16; }
        *(half8*)(smem + OFF_POLA + cg * APITCH_CG + row * APITCH_Y + col * 16) = (half8)(_Float16)0.f;
    }

    // ---- head-weight conversion (small, register-light) ----
    const int n = lane & 15, q = lane >> 4;
    half8 af_p;
    {
        const float* wp = ppw_w + n * 16 + (q & 1) * 8;
        f32x4 w0 = *(const f32x4*)wp, w1 = *(const f32x4*)(wp + 4);
        half8 t = {(_Float16)w0.x, (_Float16)w0.y, (_Float16)w0.z, (_Float16)w0.w,
                   (_Float16)w1.x, (_Float16)w1.y, (_Float16)w1.z, (_Float16)w1.w};
        af_p = (q < 2) ? t : (half8)(_Float16)0.f;   // K zero-pad 16..31
    }
    f32x4 pb = *(const f32x4*)(ppw_b + q * 4);
    half2_t pfh[8];
    #pragma unroll
    for (int j = 0; j < 8; j++) pfh[j] = pkrtz(pf_w[2 * j], pf_w[2 * j + 1]);
    half8 af0, af1;
    {
        const float* wp = vpw_w + n * 32 + q * 8;
        f32x4 w0 = *(const f32x4*)wp, w1 = *(const f32x4*)(wp + 4);
        af0 = half8{(_Float16)w0.x, (_Float16)w0.y, (_Float16)w0.z, (_Float16)w0.w,
                    (_Float16)w1.x, (_Float16)w1.y, (_Float16)w1.z, (_Float16)w1.w};
        const float* wp2 = vpw_w + (16 + n) * 32 + q * 8;
        f32x4 v0 = *(const f32x4*)wp2, v1 = *(const f32x4*)(wp2 + 4);
        af1 = half8{(_Float16)v0.x, (_Float16)v0.y, (_Float16)v0.z, (_Float16)v0.w,
                    (_Float16)v1.x, (_Float16)v1.y, (_Float16)v1.z, (_Float16)v1.w};
    }
    f32x4 vb0 = *(const f32x4*)(vpw_b + q * 4);
    f32x4 vb1 = *(const f32x4*)(vpw_b + 16 + q * 4);
    __syncthreads();

    // ================= head split: no more block barriers =================
    if (wave < 3) {
        // ---------------- policy path (waves 0,1,2) ----------------
        const int cgp = lane & 1;
        half8 wvp[9];
        #pragma unroll
        for (int t = 0; t < 9; t++) wvp[t] = *(const half8*)(smem + OFF_WPD + cgp * 144 + t * 16);
        half8 biasp = *(const half8*)(smem + OFF_WPDB + cgp * 16);

        // ph3: 1x1 16->16 via MFMA; each wave computes every tile its ph4 rows need
        const int tlo = (wave == 0) ? 0 : ((wave == 1) ? 3 : 8);
        const int thi = (wave == 0) ? 6 : ((wave == 1) ? 11 : 15);
        const int cg3 = q >> 1;
        for (int t = tlo; t < thi; t++) {
            int p = t * 16 + n;
            half8 bf = *(const half8*)(smem + OFF_X + p * XPITCH + q * 16);
            f32x4 d = __builtin_amdgcn_mfma_f32_16x16x32_f16(af_p, bf, (f32x4)(0.f), 0, 0, 0);
            if (p < NPIX) {
                int y = p / 15, x = p - y * 15;
                half2_t lo = pkrtz(fmaxf(d.x + pb.x, 0.f), fmaxf(d.y + pb.y, 0.f));
                half2_t hi = pkrtz(fmaxf(d.z + pb.z, 0.f), fmaxf(d.w + pb.w, 0.f));
                half4_t hv = {lo[0], lo[1], hi[0], hi[1]};
                *(half4_t*)(smem + OFF_POLA + cg3 * APITCH_CG + (y + 1) * APITCH_Y + (x + 1) * 16 + (q & 1) * 8) = hv;
            }
        }
        wave_fence();

        // ph4+ph5 fused: dw 3x3 + bias + relu + dot(pf) + pair-sum + store
        const int px0 = wave * 75;
        for (int i = 0; i < 3; i++) {
            int idx = i * 64 + lane;
            if (idx < 150) {
                int px = px0 + (idx >> 1);
                int y = px / 15, x = px - y * 15;
                const unsigned char* pbse = smem + OFF_POLA + cgp * APITCH_CG + y * APITCH_Y + x * 16;
                half8 acc = biasp;
                #pragma unroll
                for (int ky = 0; ky < 3; ky++) {
                    acc = __builtin_elementwise_fma(*(const half8*)(pbse + ky * APITCH_Y),      wvp[ky * 3 + 0], acc);
                    acc = __builtin_elementwise_fma(*(const half8*)(pbse + ky * APITCH_Y + 16), wvp[ky * 3 + 1], acc);
                    acc = __builtin_elementwise_fma(*(const half8*)(pbse + ky * APITCH_Y + 32), wvp[ky * 3 + 2], acc);
                }
                acc = __builtin_elementwise_max(acc, (half8)(_Float16)0.f);
                float part = 0.f;
                part = __builtin_amdgcn_fdot2(half2_t{acc[0], acc[1]}, pfh[cgp * 4 + 0], part, false);
                part = __builtin_amdgcn_fdot2(half2_t{acc[2], acc[3]}, pfh[cgp * 4 + 1], part, false);
                part = __builtin_amdgcn_fdot2(half2_t{acc[4], acc[5]}, pfh[cgp * 4 + 2], part, false);
                part = __builtin_amdgcn_fdot2(half2_t{acc[6], acc[7]}, pfh[cgp * 4 + 3], part, false);
                float tot = part + __shfl_xor(part, 1, 64);
                if (cgp == 0) out[3 * batch + b * NPIX + px] = tot;
            }
        }
    } else {
        // ---------------- value path (wave 3, whole head in-wave) ----------------
        f32x4 a0 = {0.f, 0.f, 0.f, 0.f}, a1 = {0.f, 0.f, 0.f, 0.f};
        for (int t = 0; t < 15; t++) {
            int p = t * 16 + n;
            half8 bf = *(const half8*)(smem + OFF_X + p * XPITCH + 32 + q * 16);
            f32x4 d0 = __builtin_amdgcn_mfma_f32_16x16x32_f16(af0, bf, (f32x4)(0.f), 0, 0, 0);
            f32x4 d1 = __builtin_amdgcn_mfma_f32_16x16x32_f16(af1, bf, (f32x4)(0.f), 0, 0, 0);
            if (p < NPIX) {
                #pragma unroll
                for (int r = 0; r < 4; r++) {
                    a0[r] += fmaxf(d0[r] + vb0[r], 0.f);
                    a1[r] += fmaxf(d1[r] + vb1[r], 0.f);
                }
            }
        }
        #pragma unroll
        for (int s = 1; s < 16; s <<= 1) {
            #pragma unroll
            for (int r = 0; r < 4; r++) {
                a0[r] += __shfl_xor(a0[r], s, 64);
                a1[r] += __shfl_xor(a1[r], s, 64);
            }
        }
        if (n == 0) {
            *(f32x4*)(smem + OFF_SV + q * 16)      = a0 * (1.f / 225.f);
            *(f32x4*)(smem + OFF_SV + 64 + q * 16) = a1 * (1.f / 225.f);
        }
        wave_fence();

        // FC weights read directly from global (L2-resident) -- no register prefetch
        const int o = lane & 31;
        float acc1f = vl1_b[o];
        #pragma unroll
        for (int g = 0; g < 8; g++) {
            f32x4 sv = *(const f32x4*)(smem + OFF_SV + g * 16);
            f32x4 w4 = *(const f32x4*)(vl1_w + o * 32 + g * 4);
            acc1f += sv.x * w4.x + sv.y * w4.y + sv.z * w4.z + sv.w * w4.w;
        }
        acc1f = fmaxf(acc1f, 0.f);
        if (lane < 32) *(float*)(smem + OFF_H1 + o * 4) = acc1f;
        wave_fence();

        float acc2f = vl2_b[o];
        #pragma unroll
        for (int g = 0; g < 8; g++) {
            f32x4 hv = *(const f32x4*)(smem + OFF_H1 + g * 16);
            f32x4 w4 = *(const f32x4*)(vl2_w + o * 32 + g * 4);
            acc2f += hv.x * w4.x + hv.y * w4.y + hv.z * w4.z + hv.w * w4.w;
        }
        acc2f = fmaxf(acc2f, 0.f);
        if (lane < 32) *(float*)(smem + OFF_H2 + o * 4) = acc2f;
        wave_fence();

        if (lane < 3) {
            float acc3f = vf_b[lane];
            #pragma unroll
            for (int g = 0; g < 8; g++) {
                f32x4 hv = *(const f32x4*)(smem + OFF_H2 + g * 16);
                f32x4 w4 = *(const f32x4*)(vf_w + lane * 32 + g * 4);
                acc3f += hv.x * w4.x + hv.y * w4.y + hv.z * w4.z + hv.w * w4.w;
            }
            out[b * 3 + lane] = acc3f;
        }
    }
}

extern "C" void kernel_launch(void* const* d_in, const int* in_sizes, int n_in,
                              void* d_out, int out_size, void* d_ws, size_t ws_size,
                              hipStream_t stream) {
    const float* emb    = (const float*)d_in[0];
    const float* conv_w = (const float*)d_in[1];
    const float* conv_b = (const float*)d_in[2];
    const float* ppw_w  = (const float*)d_in[3];
    const float* ppw_b  = (const float*)d_in[4];
    const float* pdw_w  = (const float*)d_in[5];
    const float* pdw_b  = (const float*)d_in[6];
    const float* pf_w   = (const float*)d_in[7];
    const float* vpw_w  = (const float*)d_in[8];
    const float* vpw_b  = (const float*)d_in[9];
    const float* vl1_w  = (const float*)d_in[10];
    const float* vl1_b  = (const float*)d_in[11];
    const float* vl2_w  = (const float*)d_in[12];
    const float* vl2_b  = (const float*)d_in[13];
    const float* vf_w   = (const float*)d_in[14];
    const float* vf_b   = (const float*)d_in[15];
    const int* sparse   = (const int*)d_in[16];
    const int* board    = (const int*)d_in[17];
    float* out = (float*)d_out;

    int batch = in_sizes[16] / 2700;  // 4096
    patnet_kernel<<<batch, NT, 0, stream>>>(
        emb, conv_w, conv_b, ppw_w, ppw_b, pdw_w, pdw_b, pf_w,
        vpw_w, vpw_b, vl1_w, vl1_b, vl2_w, vl2_b, vf_w, vf_b,
        sparse, board, out, batch);
}